// Round 5
// baseline (213.170 us; speedup 1.0000x reference)
//
#include <hip/hip_runtime.h>
#include <stdint.h>

// Shapes (fixed by the problem)
#define Bn 256
#define Un 128
#define Pn 64
#define Hn 768
#define Ototal 192   // 128 row-logit outputs + 64 col-logit outputs
#define KC 16        // split-K chunks in phase B (K=8192 -> 512 each)

#define CH 96        // floats per H-chunk in phaseA (8 iterations)
#define NIT 8        // 768 / 96
#define LDU 104      // phaseA LDS row stride (ushorts): 208B=13*16 aligned; 52dw -> 2-way alias (free)
#define LDB 72       // phaseB LDS row stride (ushorts): 144B = 9*16 aligned

typedef short s4v __attribute__((ext_vector_type(4)));
typedef short s8v __attribute__((ext_vector_type(8)));
typedef float f4v __attribute__((ext_vector_type(4)));

__device__ __forceinline__ short f2bf(float x) {
  union { float f; uint32_t u; } c; c.f = x;
  uint32_t r = (c.u + 0x7fffu + ((c.u >> 16) & 1u)) >> 16;  // RNE
  return (short)(r & 0xffffu);
}

// ---------------------------------------------------------------------------
// Kernel 1: pack weights into bf16 W'[o][k], o<128: w_utt[o,i,j]; o>=128:
// w_pheno[o-128, j, i]  (k = i*64 + j) so both logit einsums share one GEMM.
// ---------------------------------------------------------------------------
__global__ void __launch_bounds__(256) convW(const float* __restrict__ w_utt,
                                             const float* __restrict__ w_ph,
                                             ushort* __restrict__ Wbf) {
  __shared__ float tile[64 * 129];   // [j][i], +1 pad -> conflict-free columns
  const int bx = blockIdx.x;
  const int t = threadIdx.x;
  if (bx < 4096) {
    int idx = bx * 256 + t;                       // 0 .. 128*8192-1
    Wbf[idx] = (ushort)f2bf(w_utt[idx]);
    return;
  }
  const int oc = bx - 4096;                       // 0..63
  const float* src = w_ph + (size_t)oc * 8192;    // [j][i] = 64 x 128
#pragma unroll
  for (int itr = 0; itr < 8; ++itr) {
    int idx = itr * 1024 + t * 4;                 // 4 consecutive i of one j-row
    int j = idx >> 7, i = idx & 127;
    float4 v = *(const float4*)(src + idx);       // coalesced 16B
    tile[j * 129 + i + 0] = v.x;
    tile[j * 129 + i + 1] = v.y;
    tile[j * 129 + i + 2] = v.z;
    tile[j * 129 + i + 3] = v.w;
  }
  __syncthreads();
  const size_t obase = (size_t)(128 + oc) * 8192;
#pragma unroll
  for (int itr = 0; itr < 8; ++itr) {
    int k = itr * 1024 + t * 4;                   // k = i*64 + j
    int i = k >> 6, j = k & 63;
    s4v o4 = { f2bf(tile[(j + 0) * 129 + i]),
               f2bf(tile[(j + 1) * 129 + i]),
               f2bf(tile[(j + 2) * 129 + i]),
               f2bf(tile[(j + 3) * 129 + i]) };
    *(s4v*)&Wbf[obase + k] = o4;                  // coalesced 8B
  }
}

// ---------------------------------------------------------------------------
// Kernel 2: cosine-sim matrix, 2 blocks/batch, 512 thr.
// CH=96: 8 iterations; LDS double-buffered by ADDRESS parity (no register
// arrays -> no spill); ONE barrier per iteration. Per thread per iter:
// 3 float4 u + 3 float4 p in flight. c[b,i,j] = (u_i.p_j)*inu_i*inp_j.
// ---------------------------------------------------------------------------
__global__ void __launch_bounds__(512) phaseA(const float* __restrict__ utt,
                                              const float* __restrict__ ph,
                                              ushort* __restrict__ Cbf) {
  const int bx = blockIdx.x;
  const int b = bx >> 1, half = bx & 1;
  const int t = threadIdx.x;          // 0..511
  const int w = t >> 6, l = t & 63;

  __shared__ short uA[2][64 * LDU];   // 2 x 13 KiB
  __shared__ short pB[2][64 * LDU];   // 2 x 13 KiB
  __shared__ float s_inu[64];
  __shared__ float s_inp[64];

  const int r  = t >> 3;              // 0..63 (row for both u-half and p)
  const int c12 = (t & 7) * 12;       // col start within 96-float chunk

  const size_t rstride = (size_t)Bn * Hn;
  const float* ubase = utt + (size_t)b * Hn + (size_t)(half * 64 + r) * rstride + c12;
  const float* pbase = ph  + (size_t)b * Hn + (size_t)r * rstride + c12;

  // single named prefetch set (1-deep): 3 f4 u + 3 f4 p
  float4 u0 = *(const float4*)(ubase + 0);
  float4 u1 = *(const float4*)(ubase + 4);
  float4 u2 = *(const float4*)(ubase + 8);
  float4 p0 = *(const float4*)(pbase + 0);
  float4 p1 = *(const float4*)(pbase + 4);
  float4 p2 = *(const float4*)(pbase + 8);

  float ssu = 0.f, ssp = 0.f;
  f4v zero4 = {0.f, 0.f, 0.f, 0.f};
  f4v acc0 = zero4, acc1 = zero4;

  const int m  = l & 15;
  const int ko = (l >> 4) * 8;
  const int it = w & 3;               // i-tile (16 rows), 0..3
  const int jp = w >> 2;              // j-half (32 cols), 0..1
  const int lw = r * LDU + c12;       // LDS write offset (elements)

#pragma unroll
  for (int c = 0; c < NIT; ++c) {
    const int s = c & 1;
    // consume prefetched regs: sumsq + convert + LDS store (buffer s)
    float4 a0 = u0, a1 = u1, a2 = u2, q0 = p0, q1 = p1, q2 = p2;
    ssu += a0.x*a0.x + a0.y*a0.y + a0.z*a0.z + a0.w*a0.w
         + a1.x*a1.x + a1.y*a1.y + a1.z*a1.z + a1.w*a1.w
         + a2.x*a2.x + a2.y*a2.y + a2.z*a2.z + a2.w*a2.w;
    ssp += q0.x*q0.x + q0.y*q0.y + q0.z*q0.z + q0.w*q0.w
         + q1.x*q1.x + q1.y*q1.y + q1.z*q1.z + q1.w*q1.w
         + q2.x*q2.x + q2.y*q2.y + q2.z*q2.z + q2.w*q2.w;
    s4v ua0 = { f2bf(a0.x), f2bf(a0.y), f2bf(a0.z), f2bf(a0.w) };
    s4v ua1 = { f2bf(a1.x), f2bf(a1.y), f2bf(a1.z), f2bf(a1.w) };
    s4v ua2 = { f2bf(a2.x), f2bf(a2.y), f2bf(a2.z), f2bf(a2.w) };
    s4v pa0 = { f2bf(q0.x), f2bf(q0.y), f2bf(q0.z), f2bf(q0.w) };
    s4v pa1 = { f2bf(q1.x), f2bf(q1.y), f2bf(q1.z), f2bf(q1.w) };
    s4v pa2 = { f2bf(q2.x), f2bf(q2.y), f2bf(q2.z), f2bf(q2.w) };
    *(s4v*)&uA[s][lw + 0] = ua0;
    *(s4v*)&uA[s][lw + 4] = ua1;
    *(s4v*)&uA[s][lw + 8] = ua2;
    *(s4v*)&pB[s][lw + 0] = pa0;
    *(s4v*)&pB[s][lw + 4] = pa1;
    *(s4v*)&pB[s][lw + 8] = pa2;
    __syncthreads();                  // the ONLY barrier per iteration
    // issue next chunk's loads (drain at next iteration's convert)
    if (c + 1 < NIT) {
      u0 = *(const float4*)(ubase + (c + 1) * CH + 0);
      u1 = *(const float4*)(ubase + (c + 1) * CH + 4);
      u2 = *(const float4*)(ubase + (c + 1) * CH + 8);
      p0 = *(const float4*)(pbase + (c + 1) * CH + 0);
      p1 = *(const float4*)(pbase + (c + 1) * CH + 4);
      p2 = *(const float4*)(pbase + (c + 1) * CH + 8);
    }
    // MFMA on buffer s: 3 k-steps of 32
    const short* ab = &uA[s][(it * 16 + m) * LDU + ko];
    const short* bb = &pB[s][(jp * 32 + m) * LDU + ko];
#pragma unroll
    for (int ks = 0; ks < 3; ++ks) {
      s8v af  = *(const s8v*)(ab + ks * 32);
      s8v bf0 = *(const s8v*)(bb + ks * 32);
      s8v bf1 = *(const s8v*)(bb + 16 * LDU + ks * 32);
      acc0 = __builtin_amdgcn_mfma_f32_16x16x32_bf16(af, bf0, acc0, 0, 0, 0);
      acc1 = __builtin_amdgcn_mfma_f32_16x16x32_bf16(af, bf1, acc1, 0, 0, 0);
    }
  }

  // row sumsq reductions: 8 threads/row are adjacent lanes
  ssu += __shfl_xor(ssu, 4); ssu += __shfl_xor(ssu, 2); ssu += __shfl_xor(ssu, 1);
  ssp += __shfl_xor(ssp, 4); ssp += __shfl_xor(ssp, 2); ssp += __shfl_xor(ssp, 1);
  if ((t & 7) == 0) {
    s_inu[r] = 1.f / fmaxf(sqrtf(ssu), 1e-8f);
    s_inp[r] = 1.f / fmaxf(sqrtf(ssp), 1e-8f);
  }
  __syncthreads();

  // epilogue: scale, store bf16 C[b][half*64+i][j]
  // D layout (verified m89/m91): col = lane&15, row = (lane>>4)*4 + reg
  const int cl = l & 15;
  const int rq = (l >> 4) * 4;
#pragma unroll
  for (int jt = 0; jt < 2; ++jt) {
    int j = jp * 32 + jt * 16 + cl;
    float sj = s_inp[j];
    f4v a = (jt == 0) ? acc0 : acc1;
#pragma unroll
    for (int rr = 0; rr < 4; ++rr) {
      int il = it * 16 + rq + rr;     // local row 0..63
      float v = a[rr] * s_inu[il] * sj;
      Cbf[((size_t)b * Un + half * 64 + il) * Pn + j] = (ushort)f2bf(v);
    }
  }
}

// ---------------------------------------------------------------------------
// Kernel 3: logits GEMM, M=256, N=192, K=8192, split-K (KC=16).
// 8 stages of K=64.
// ---------------------------------------------------------------------------
__global__ void __launch_bounds__(256) phaseB(const ushort* __restrict__ Cbf,
                                              const ushort* __restrict__ Wbf,
                                              float* __restrict__ partial) {
  const int kc = blockIdx.x;
  const int mt = blockIdx.y;
  const int nt = blockIdx.z;
  const int t = threadIdx.x;
  const int w = t >> 6, l = t & 63;

  __shared__ short Ab[64 * LDB];
  __shared__ short Bb[64 * LDB];

  const int row = t >> 2;          // 0..63
  const int k16 = (t & 3) * 16;    // 16 elems per thread per stage-row

  f4v zero4 = {0.f, 0.f, 0.f, 0.f};
  f4v acc[4] = {zero4, zero4, zero4, zero4};

  const ushort* Ag = Cbf + (size_t)(mt * 64 + row) * 8192 + kc * 512 + k16;
  const ushort* Bg = Wbf + (size_t)(nt * 64 + row) * 8192 + kc * 512 + k16;
  const int m  = l & 15;
  const int ko = (l >> 4) * 8;

  for (int c = 0; c < 8; ++c) {
    s8v av0 = *(const s8v*)(Ag + c * 64);
    s8v av1 = *(const s8v*)(Ag + c * 64 + 8);
    s8v bv0 = *(const s8v*)(Bg + c * 64);
    s8v bv1 = *(const s8v*)(Bg + c * 64 + 8);
    __syncthreads();
    *(s8v*)&Ab[row * LDB + k16]     = av0;
    *(s8v*)&Ab[row * LDB + k16 + 8] = av1;
    *(s8v*)&Bb[row * LDB + k16]     = bv0;
    *(s8v*)&Bb[row * LDB + k16 + 8] = bv1;
    __syncthreads();
#pragma unroll
    for (int ks = 0; ks < 2; ++ks) {
      s8v af = *(const s8v*)&Ab[(16 * w + m) * LDB + ks * 32 + ko];
#pragma unroll
      for (int jt = 0; jt < 4; ++jt) {
        s8v bf = *(const s8v*)&Bb[(16 * jt + m) * LDB + ks * 32 + ko];
        acc[jt] = __builtin_amdgcn_mfma_f32_16x16x32_bf16(af, bf, acc[jt], 0, 0, 0);
      }
    }
  }

  const int rq = (l >> 4) * 4;
#pragma unroll
  for (int jt = 0; jt < 4; ++jt) {
    int og = nt * 64 + 16 * jt + (l & 15);
#pragma unroll
    for (int r = 0; r < 4; ++r) {
      int bg = mt * 64 + 16 * w + rq + r;
      partial[((size_t)kc * Bn + bg) * Ototal + og] = acc[jt][r];
    }
  }
}

// ---------------------------------------------------------------------------
// Kernel 4: reduce split-K partials + bias + dual-group softmax.
// ---------------------------------------------------------------------------
__global__ void __launch_bounds__(192) phaseC(const float* __restrict__ partial,
                                              const float* __restrict__ b_utt,
                                              const float* __restrict__ b_ph,
                                              float* __restrict__ out) {
  const int b = blockIdx.x;
  const int t = threadIdx.x;      // 0..191
  const int w = t >> 6, l = t & 63;

  float v = 0.f;
#pragma unroll
  for (int kc = 0; kc < KC; ++kc)
    v += partial[((size_t)kc * Bn + b) * Ototal + t];
  v += (t < Un) ? b_utt[t] : b_ph[t - Un];

  __shared__ float red[3];
  float mx = v;
  for (int o = 32; o >= 1; o >>= 1) mx = fmaxf(mx, __shfl_xor(mx, o));
  if (l == 0) red[w] = mx;
  __syncthreads();
  float gmax = (t < Un) ? fmaxf(red[0], red[1]) : red[2];
  float e = expf(v - gmax);
  float s = e;
  for (int o = 32; o >= 1; o >>= 1) s += __shfl_xor(s, o);
  __syncthreads();
  if (l == 0) red[w] = s;
  __syncthreads();
  float gs = (t < Un) ? (red[0] + red[1]) : red[2];
  float r = e / gs;
  if (t < Un) out[(size_t)b * Un + t] = r;
  else        out[(size_t)Bn * Un + (size_t)b * Pn + (t - Un)] = r;
}

// ---------------------------------------------------------------------------
extern "C" void kernel_launch(void* const* d_in, const int* in_sizes, int n_in,
                              void* d_out, int out_size, void* d_ws, size_t ws_size,
                              hipStream_t stream) {
  const float* utt   = (const float*)d_in[0];  // [128,256,768]
  const float* ph    = (const float*)d_in[1];  // [64,256,768]
  const float* w_utt = (const float*)d_in[2];  // [128,128,64]
  const float* b_utt = (const float*)d_in[3];  // [128]
  const float* w_ph  = (const float*)d_in[4];  // [64,64,128]
  const float* b_ph  = (const float*)d_in[5];  // [64]

  char* ws = (char*)d_ws;
  ushort* Cbf     = (ushort*)(ws);                 // 256*128*64*2  = 4 MiB
  ushort* Wbf     = (ushort*)(ws + 4194304);       // 192*8192*2   = 3 MiB
  float*  partial = (float*)(ws + 7340032);        // 16*256*192*4 = 3 MiB

  convW <<<dim3(4096 + 64), dim3(256), 0, stream>>>(w_utt, w_ph, Wbf);
  phaseA<<<dim3(2 * Bn), dim3(512), 0, stream>>>(utt, ph, Cbf);
  phaseB<<<dim3(KC, 4, 3), dim3(256), 0, stream>>>(Cbf, Wbf, partial);
  phaseC<<<dim3(Bn), dim3(192), 0, stream>>>(partial, b_utt, b_ph, (float*)d_out);
}